// Round 1
// baseline (71289.618 us; speedup 1.0000x reference)
//
#include <hip/hip_runtime.h>
#include <hip/hip_bf16.h>
#include <math.h>

// Problem constants (fixed by the reference)
#define T_STEPS 6
#define N_NODES 50000
#define IN_DIM  256
#define HID     256
#define R_REL   4
#define E_EDGES 800000
#define G3      768   // 3*HID

// ---------------------------------------------------------------------------
// Transpose W [rows, cols] -> WT [cols, rows]
__global__ void transpose_w(const float* __restrict__ W, float* __restrict__ WT,
                            int rows, int cols) {
    int idx = blockIdx.x * blockDim.x + threadIdx.x;
    if (idx >= rows * cols) return;
    int rr = idx / cols, cc = idx % cols;
    WT[(size_t)cc * rows + rr] = W[idx];
}

// ---------------------------------------------------------------------------
// Edge scatter: tmp[row] += w * x[col] (256-wide), rowsum[row] += w
// One wave (64 lanes) per edge; lane l handles channels 4l..4l+3.
__global__ void scatter_agg(const float* __restrict__ x,
                            const int* __restrict__ row,
                            const int* __restrict__ col,
                            const float* __restrict__ w,
                            float* __restrict__ tmp,
                            float* __restrict__ rowsum,
                            int E) {
    int gw   = (blockIdx.x * blockDim.x + threadIdx.x) >> 6;
    int lane = threadIdx.x & 63;
    int nw   = (gridDim.x * blockDim.x) >> 6;
    for (int e = gw; e < E; e += nw) {
        int   rI = row[e];
        int   cI = col[e];
        float we = w[e];
        const float4* xr = (const float4*)(x + (size_t)cI * 256);
        float4 xv = xr[lane];
        float* dst = tmp + (size_t)rI * 256 + lane * 4;
        atomicAdd(dst + 0, we * xv.x);
        atomicAdd(dst + 1, we * xv.y);
        atomicAdd(dst + 2, we * xv.z);
        atomicAdd(dst + 3, we * xv.w);
        if (lane == 0) atomicAdd(rowsum + rI, we);
    }
}

// ---------------------------------------------------------------------------
// C[M,Nc] = A[M,256] @ B[256,Nc] (+ rowscale[i]*bias[j] or bias[j]) (+relu)
// 64x64 tile, 256 threads, 4x4 micro-tile per thread. K fixed = 256.
__global__ __launch_bounds__(256)
void sgemm(const float* __restrict__ A, const float* __restrict__ B,
           float* __restrict__ C, int M, int Nc,
           const float* __restrict__ bias, const float* __restrict__ rowscale,
           int do_relu) {
    __shared__ float AsT[16][64];   // transposed A tile: [k][row]
    __shared__ float Bs[16][64];    // [k][col]
    int m0 = blockIdx.x * 64, n0 = blockIdx.y * 64;
    int tid = threadIdx.x;
    int tx = tid & 15, ty = tid >> 4;
    float acc[4][4] = {{0.f}};

    int ar = tid >> 2;            // 0..63 (row within tile)
    int ak = (tid & 3) * 4;       // k sub-offset
    int bk = tid >> 4;            // 0..15
    int bn = (tid & 15) * 4;
    bool arow_ok = (m0 + ar) < M;
    const float* Aptr = A + (size_t)(m0 + ar) * 256 + ak;

    for (int k0 = 0; k0 < 256; k0 += 16) {
        float4 av = arow_ok ? *(const float4*)(Aptr + k0) : make_float4(0, 0, 0, 0);
        float4 bv = *(const float4*)(B + (size_t)(k0 + bk) * Nc + n0 + bn);
        AsT[ak + 0][ar] = av.x;
        AsT[ak + 1][ar] = av.y;
        AsT[ak + 2][ar] = av.z;
        AsT[ak + 3][ar] = av.w;
        *(float4*)&Bs[bk][bn] = bv;
        __syncthreads();
#pragma unroll
        for (int kk = 0; kk < 16; ++kk) {
            float4 a4 = *(const float4*)&AsT[kk][ty * 4];
            float4 b4 = *(const float4*)&Bs[kk][tx * 4];
            float a_[4] = {a4.x, a4.y, a4.z, a4.w};
            float b_[4] = {b4.x, b4.y, b4.z, b4.w};
#pragma unroll
            for (int i = 0; i < 4; ++i)
#pragma unroll
                for (int j = 0; j < 4; ++j)
                    acc[i][j] = fmaf(a_[i], b_[j], acc[i][j]);
        }
        __syncthreads();
    }

#pragma unroll
    for (int i = 0; i < 4; ++i) {
        int gr = m0 + ty * 4 + i;
        if (gr >= M) continue;
        float rs = rowscale ? rowscale[gr] : 1.0f;
        float4 o;
        float* op = &o.x;
#pragma unroll
        for (int j = 0; j < 4; ++j) {
            int gc = n0 + tx * 4 + j;
            float v = acc[i][j];
            if (bias) v += rs * bias[gc];
            if (do_relu) v = fmaxf(v, 0.f);
            op[j] = v;
        }
        *(float4*)(C + (size_t)gr * Nc + n0 + tx * 4) = o;
    }
}

// ---------------------------------------------------------------------------
// Relation attention + combine: block per node, 256 threads (one per channel)
__global__ void attn_combine(const float* __restrict__ msgs,
                             const float* __restrict__ q,
                             float* __restrict__ s, int N) {
    int n = blockIdx.x, j = threadIdx.x;
    size_t NH = (size_t)N * 256;
    size_t base = (size_t)n * 256 + j;
    float m0 = msgs[0 * NH + base];
    float m1 = msgs[1 * NH + base];
    float m2 = msgs[2 * NH + base];
    float m3 = msgs[3 * NH + base];
    float qv = q[j];
    float v0 = m0 * qv, v1 = m1 * qv, v2 = m2 * qv, v3 = m3 * qv;
#pragma unroll
    for (int off = 32; off; off >>= 1) {
        v0 += __shfl_xor(v0, off);
        v1 += __shfl_xor(v1, off);
        v2 += __shfl_xor(v2, off);
        v3 += __shfl_xor(v3, off);
    }
    __shared__ float part[4][4];
    __shared__ float alpha[4];
    int wid = j >> 6, lane = j & 63;
    if (lane == 0) {
        part[0][wid] = v0; part[1][wid] = v1; part[2][wid] = v2; part[3][wid] = v3;
    }
    __syncthreads();
    if (j == 0) {
        float d[4];
#pragma unroll
        for (int r = 0; r < 4; ++r) d[r] = part[r][0] + part[r][1] + part[r][2] + part[r][3];
        float mx = fmaxf(fmaxf(d[0], d[1]), fmaxf(d[2], d[3]));
        float e[4], sum = 0.f;
#pragma unroll
        for (int r = 0; r < 4; ++r) { e[r] = expf(d[r] - mx); sum += e[r]; }
#pragma unroll
        for (int r = 0; r < 4; ++r) alpha[r] = e[r] / sum;
    }
    __syncthreads();
    float sv = alpha[0] * m0 + alpha[1] * m1 + alpha[2] * m2 + alpha[3] * m3;
    s[(size_t)n * 256 + j] = fmaxf(sv, 0.f);
}

// ---------------------------------------------------------------------------
// GRU gate fuse: h = (1-z)*n + z*h  (torch gate order r,z,n)
__global__ void gru_gate(const float* __restrict__ gi, const float* __restrict__ gh,
                         float* __restrict__ h, int total) {
    int idx = blockIdx.x * blockDim.x + threadIdx.x;
    if (idx >= total) return;
    int i = idx >> 8, j = idx & 255;
    size_t b = (size_t)i * 768;
    float ir = gi[b + j],       hr = gh[b + j];
    float iz = gi[b + 256 + j], hz = gh[b + 256 + j];
    float in_ = gi[b + 512 + j], hn = gh[b + 512 + j];
    float r = 1.f / (1.f + expf(-(ir + hr)));
    float z = 1.f / (1.f + expf(-(iz + hz)));
    float ng = tanhf(in_ + r * hn);
    float hv = h[idx];
    h[idx] = (1.f - z) * ng + z * hv;
}

// ---------------------------------------------------------------------------
// out[n] = dot(h1[n,:], W2[:,0]) + b2[0]
__global__ void classifier_out(const float* __restrict__ h1, const float* __restrict__ W2,
                               const float* __restrict__ b2, float* __restrict__ out, int N) {
    int n = blockIdx.x, j = threadIdx.x;
    float v = h1[(size_t)n * 256 + j] * W2[j];
#pragma unroll
    for (int off = 32; off; off >>= 1) v += __shfl_xor(v, off);
    __shared__ float part[4];
    if ((j & 63) == 0) part[j >> 6] = v;
    __syncthreads();
    if (j == 0) out[n] = part[0] + part[1] + part[2] + part[3] + b2[0];
}

// ---------------------------------------------------------------------------
extern "C" void kernel_launch(void* const* d_in, const int* in_sizes, int n_in,
                              void* d_out, int out_size, void* d_ws, size_t ws_size,
                              hipStream_t stream) {
    const float* feat  = (const float*)d_in[0];
    const int*   erow  = (const int*)d_in[1];
    const int*   ecol  = (const int*)d_in[2];
    const float* ew    = (const float*)d_in[3];
    const float* W_rel = (const float*)d_in[4];
    const float* b_rel = (const float*)d_in[5];
    const float* rq    = (const float*)d_in[6];
    const float* Wih   = (const float*)d_in[7];
    const float* Whh   = (const float*)d_in[8];
    const float* bih   = (const float*)d_in[9];
    const float* bhh   = (const float*)d_in[10];
    const float* W1    = (const float*)d_in[11];
    const float* b1    = (const float*)d_in[12];
    const float* W2    = (const float*)d_in[13];
    const float* b2    = (const float*)d_in[14];
    float* out = (float*)d_out;

    const int N = N_NODES;
    char* ws = (char*)d_ws;
    // layout (bytes):
    size_t off_msgs   = 0;                          // 204,800,000  (also gh)
    size_t off_gi     = off_msgs + (size_t)R_REL * N * HID * 4;     // 153,600,000
    size_t off_tmp    = off_gi + (size_t)N * G3 * 4;                // 51,200,000 (agg / s / h1)
    size_t off_rowsum = off_tmp + (size_t)N * HID * 4;              // 200,000
    size_t off_h      = off_rowsum + (size_t)N * 4;                 // 51,200,000
    size_t off_wiht   = off_h + (size_t)N * HID * 4;                // 786,432
    size_t off_whht   = off_wiht + (size_t)HID * G3 * 4;            // 786,432

    float* msgs   = (float*)(ws + off_msgs);
    float* gh     = msgs;                 // alias: msgs dead before gh written
    float* gi     = (float*)(ws + off_gi);
    float* tmp    = (float*)(ws + off_tmp);   // agg buffer; aliased as s and h1
    float* s      = tmp;
    float* h1     = tmp;
    float* rowsum = (float*)(ws + off_rowsum);
    float* h      = (float*)(ws + off_h);
    float* WihT   = (float*)(ws + off_wiht);
    float* WhhT   = (float*)(ws + off_whht);

    // one-time prep
    {
        int total = G3 * HID;
        transpose_w<<<(total + 255) / 256, 256, 0, stream>>>(Wih, WihT, G3, HID);
        transpose_w<<<(total + 255) / 256, 256, 0, stream>>>(Whh, WhhT, G3, HID);
    }
    hipMemsetAsync(h, 0, (size_t)N * HID * 4, stream);

    dim3 gemm_grid_h((N + 63) / 64, HID / 64);   // Nc=256
    dim3 gemm_grid_g((N + 63) / 64, G3 / 64);    // Nc=768
    int scatter_blocks = (E_EDGES * 64) / 256;

    for (int t = 0; t < T_STEPS; ++t) {
        const float* x_t = feat + (size_t)t * N * IN_DIM;
        for (int r = 0; r < R_REL; ++r) {
            // zero tmp + rowsum in one contiguous memset
            hipMemsetAsync(tmp, 0, (size_t)N * HID * 4 + (size_t)N * 4, stream);
            size_t eoff = ((size_t)t * R_REL + r) * E_EDGES;
            scatter_agg<<<scatter_blocks, 256, 0, stream>>>(
                x_t, erow + eoff, ecol + eoff, ew + eoff, tmp, rowsum, E_EDGES);
            sgemm<<<gemm_grid_h, 256, 0, stream>>>(
                tmp, W_rel + (size_t)r * HID * HID, msgs + (size_t)r * N * HID,
                N, HID, b_rel + (size_t)r * HID, rowsum, 0);
        }
        attn_combine<<<N, 256, 0, stream>>>(msgs, rq, s, N);
        sgemm<<<gemm_grid_g, 256, 0, stream>>>(s, WihT, gi, N, G3, bih, nullptr, 0);
        sgemm<<<gemm_grid_g, 256, 0, stream>>>(h, WhhT, gh, N, G3, bhh, nullptr, 0);
        gru_gate<<<(N * HID + 255) / 256, 256, 0, stream>>>(gi, gh, h, N * HID);
    }

    // classifier
    sgemm<<<gemm_grid_h, 256, 0, stream>>>(h, W1, h1, N, HID, b1, nullptr, 1);
    classifier_out<<<N, 256, 0, stream>>>(h1, W2, b2, out, N);
}

// Round 2
// 13457.039 us; speedup vs baseline: 5.2976x; 5.2976x over previous
//
#include <hip/hip_runtime.h>
#include <hip/hip_bf16.h>
#include <math.h>

// Problem constants (fixed by the reference)
#define T_STEPS 6
#define N_NODES 50000
#define IN_DIM  256
#define HID     256
#define R_REL   4
#define E_EDGES 800000
#define G3      768   // 3*HID

// ---------------------------------------------------------------------------
// Transpose W [rows, cols] -> WT [cols, rows]
__global__ void transpose_w(const float* __restrict__ W, float* __restrict__ WT,
                            int rows, int cols) {
    int idx = blockIdx.x * blockDim.x + threadIdx.x;
    if (idx >= rows * cols) return;
    int rr = idx / cols, cc = idx % cols;
    WT[(size_t)cc * rows + rr] = W[idx];
}

// ---------------------------------------------------------------------------
// CSR build step 1: histogram of destination rows
__global__ void hist_rows(const int* __restrict__ row, int* __restrict__ counts, int E) {
    int e = blockIdx.x * blockDim.x + threadIdx.x;
    if (e < E) atomicAdd(&counts[row[e]], 1);
}

// CSR build step 2: exclusive prefix scan (single block, 1024 threads)
__global__ __launch_bounds__(1024)
void scan_block(const int* __restrict__ counts, int* __restrict__ starts, int n) {
    __shared__ int temp[1024];
    __shared__ int carry;
    if (threadIdx.x == 0) carry = 0;
    __syncthreads();
    for (int base = 0; base < n; base += 1024) {
        int i = base + (int)threadIdx.x;
        int v = (i < n) ? counts[i] : 0;
        temp[threadIdx.x] = v;
        __syncthreads();
#pragma unroll
        for (int off = 1; off < 1024; off <<= 1) {
            int t = (threadIdx.x >= (unsigned)off) ? temp[threadIdx.x - off] : 0;
            __syncthreads();
            temp[threadIdx.x] += t;
            __syncthreads();
        }
        int incl = temp[threadIdx.x];
        if (i < n) starts[i] = carry + incl - v;
        __syncthreads();
        if (threadIdx.x == 1023) carry += incl;
        __syncthreads();
    }
    if (threadIdx.x == 0) starts[n] = carry;
}

// CSR build step 3: scatter (col, w) into row-sorted slots
__global__ void bin_fill(const int* __restrict__ row, const int* __restrict__ col,
                         const float* __restrict__ w, const int* __restrict__ starts,
                         int* __restrict__ cursor, int2* __restrict__ colw, int E) {
    int e = blockIdx.x * blockDim.x + threadIdx.x;
    if (e >= E) return;
    int r = row[e];
    int pos = starts[r] + atomicAdd(&cursor[r], 1);
    colw[pos] = make_int2(col[e], __float_as_int(w[e]));
}

// Aggregation: one wave per destination row, gather+accumulate, single write.
// Also emits rowsum (sum of edge weights) for the bias term.
__global__ void csr_agg(const float* __restrict__ x, const int2* __restrict__ colw,
                        const int* __restrict__ starts, float* __restrict__ tmp,
                        float* __restrict__ rowsum, int N) {
    int wid  = (blockIdx.x * blockDim.x + threadIdx.x) >> 6;
    int lane = threadIdx.x & 63;
    if (wid >= N) return;
    int s0 = starts[wid], s1 = starts[wid + 1];
    float4 acc = make_float4(0.f, 0.f, 0.f, 0.f);
    float wsum = 0.f;
    for (int e = s0; e < s1; ++e) {
        int2 cw = colw[e];
        float we = __int_as_float(cw.y);
        float4 xv = ((const float4*)(x + (size_t)cw.x * 256))[lane];
        acc.x = fmaf(we, xv.x, acc.x);
        acc.y = fmaf(we, xv.y, acc.y);
        acc.z = fmaf(we, xv.z, acc.z);
        acc.w = fmaf(we, xv.w, acc.w);
        wsum += we;
    }
    ((float4*)(tmp + (size_t)wid * 256))[lane] = acc;
    if (lane == 0) rowsum[wid] = wsum;
}

// ---------------------------------------------------------------------------
// C[M,Nc] = A[M,256] @ B[256,Nc] (+ rowscale[i]*bias[j] or bias[j]) (+relu)
// 64x64 tile, 256 threads, 4x4 micro-tile per thread. K fixed = 256.
__global__ __launch_bounds__(256)
void sgemm(const float* __restrict__ A, const float* __restrict__ B,
           float* __restrict__ C, int M, int Nc,
           const float* __restrict__ bias, const float* __restrict__ rowscale,
           int do_relu) {
    __shared__ float AsT[16][64];   // transposed A tile: [k][row]
    __shared__ float Bs[16][64];    // [k][col]
    int m0 = blockIdx.x * 64, n0 = blockIdx.y * 64;
    int tid = threadIdx.x;
    int tx = tid & 15, ty = tid >> 4;
    float acc[4][4] = {{0.f}};

    int ar = tid >> 2;            // 0..63 (row within tile)
    int ak = (tid & 3) * 4;       // k sub-offset
    int bk = tid >> 4;            // 0..15
    int bn = (tid & 15) * 4;
    bool arow_ok = (m0 + ar) < M;
    const float* Aptr = A + (size_t)(m0 + ar) * 256 + ak;

    for (int k0 = 0; k0 < 256; k0 += 16) {
        float4 av = arow_ok ? *(const float4*)(Aptr + k0) : make_float4(0, 0, 0, 0);
        float4 bv = *(const float4*)(B + (size_t)(k0 + bk) * Nc + n0 + bn);
        AsT[ak + 0][ar] = av.x;
        AsT[ak + 1][ar] = av.y;
        AsT[ak + 2][ar] = av.z;
        AsT[ak + 3][ar] = av.w;
        *(float4*)&Bs[bk][bn] = bv;
        __syncthreads();
#pragma unroll
        for (int kk = 0; kk < 16; ++kk) {
            float4 a4 = *(const float4*)&AsT[kk][ty * 4];
            float4 b4 = *(const float4*)&Bs[kk][tx * 4];
            float a_[4] = {a4.x, a4.y, a4.z, a4.w};
            float b_[4] = {b4.x, b4.y, b4.z, b4.w};
#pragma unroll
            for (int i = 0; i < 4; ++i)
#pragma unroll
                for (int j = 0; j < 4; ++j)
                    acc[i][j] = fmaf(a_[i], b_[j], acc[i][j]);
        }
        __syncthreads();
    }

#pragma unroll
    for (int i = 0; i < 4; ++i) {
        int gr = m0 + ty * 4 + i;
        if (gr >= M) continue;
        float rs = rowscale ? rowscale[gr] : 1.0f;
        float4 o;
        float* op = &o.x;
#pragma unroll
        for (int j = 0; j < 4; ++j) {
            int gc = n0 + tx * 4 + j;
            float v = acc[i][j];
            if (bias) v += rs * bias[gc];
            if (do_relu) v = fmaxf(v, 0.f);
            op[j] = v;
        }
        *(float4*)(C + (size_t)gr * Nc + n0 + tx * 4) = o;
    }
}

// ---------------------------------------------------------------------------
// Relation attention + combine: block per node, 256 threads (one per channel)
__global__ void attn_combine(const float* __restrict__ msgs,
                             const float* __restrict__ q,
                             float* __restrict__ s, int N) {
    int n = blockIdx.x, j = threadIdx.x;
    size_t NH = (size_t)N * 256;
    size_t base = (size_t)n * 256 + j;
    float m0 = msgs[0 * NH + base];
    float m1 = msgs[1 * NH + base];
    float m2 = msgs[2 * NH + base];
    float m3 = msgs[3 * NH + base];
    float qv = q[j];
    float v0 = m0 * qv, v1 = m1 * qv, v2 = m2 * qv, v3 = m3 * qv;
#pragma unroll
    for (int off = 32; off; off >>= 1) {
        v0 += __shfl_xor(v0, off);
        v1 += __shfl_xor(v1, off);
        v2 += __shfl_xor(v2, off);
        v3 += __shfl_xor(v3, off);
    }
    __shared__ float part[4][4];
    __shared__ float alpha[4];
    int wid = j >> 6, lane = j & 63;
    if (lane == 0) {
        part[0][wid] = v0; part[1][wid] = v1; part[2][wid] = v2; part[3][wid] = v3;
    }
    __syncthreads();
    if (j == 0) {
        float d[4];
#pragma unroll
        for (int r = 0; r < 4; ++r) d[r] = part[r][0] + part[r][1] + part[r][2] + part[r][3];
        float mx = fmaxf(fmaxf(d[0], d[1]), fmaxf(d[2], d[3]));
        float e[4], sum = 0.f;
#pragma unroll
        for (int r = 0; r < 4; ++r) { e[r] = expf(d[r] - mx); sum += e[r]; }
#pragma unroll
        for (int r = 0; r < 4; ++r) alpha[r] = e[r] / sum;
    }
    __syncthreads();
    float sv = alpha[0] * m0 + alpha[1] * m1 + alpha[2] * m2 + alpha[3] * m3;
    s[(size_t)n * 256 + j] = fmaxf(sv, 0.f);
}

// ---------------------------------------------------------------------------
// GRU gate fuse: h = (1-z)*n + z*h  (torch gate order r,z,n)
__global__ void gru_gate(const float* __restrict__ gi, const float* __restrict__ gh,
                         float* __restrict__ h, int total) {
    int idx = blockIdx.x * blockDim.x + threadIdx.x;
    if (idx >= total) return;
    int i = idx >> 8, j = idx & 255;
    size_t b = (size_t)i * 768;
    float ir = gi[b + j],       hr = gh[b + j];
    float iz = gi[b + 256 + j], hz = gh[b + 256 + j];
    float in_ = gi[b + 512 + j], hn = gh[b + 512 + j];
    float r = 1.f / (1.f + expf(-(ir + hr)));
    float z = 1.f / (1.f + expf(-(iz + hz)));
    float ng = tanhf(in_ + r * hn);
    float hv = h[idx];
    h[idx] = (1.f - z) * ng + z * hv;
}

// ---------------------------------------------------------------------------
// out[n] = dot(h1[n,:], W2[:,0]) + b2[0]
__global__ void classifier_out(const float* __restrict__ h1, const float* __restrict__ W2,
                               const float* __restrict__ b2, float* __restrict__ out, int N) {
    int n = blockIdx.x, j = threadIdx.x;
    float v = h1[(size_t)n * 256 + j] * W2[j];
#pragma unroll
    for (int off = 32; off; off >>= 1) v += __shfl_xor(v, off);
    __shared__ float part[4];
    if ((j & 63) == 0) part[j >> 6] = v;
    __syncthreads();
    if (j == 0) out[n] = part[0] + part[1] + part[2] + part[3] + b2[0];
}

// ---------------------------------------------------------------------------
extern "C" void kernel_launch(void* const* d_in, const int* in_sizes, int n_in,
                              void* d_out, int out_size, void* d_ws, size_t ws_size,
                              hipStream_t stream) {
    const float* feat  = (const float*)d_in[0];
    const int*   erow  = (const int*)d_in[1];
    const int*   ecol  = (const int*)d_in[2];
    const float* ew    = (const float*)d_in[3];
    const float* W_rel = (const float*)d_in[4];
    const float* b_rel = (const float*)d_in[5];
    const float* rq    = (const float*)d_in[6];
    const float* Wih   = (const float*)d_in[7];
    const float* Whh   = (const float*)d_in[8];
    const float* bih   = (const float*)d_in[9];
    const float* bhh   = (const float*)d_in[10];
    const float* W1    = (const float*)d_in[11];
    const float* b1    = (const float*)d_in[12];
    const float* W2    = (const float*)d_in[13];
    const float* b2    = (const float*)d_in[14];
    float* out = (float*)d_out;

    const int N = N_NODES;
    char* ws = (char*)d_ws;
    // layout (bytes), all 16B-aligned:
    size_t off_msgs   = 0;                                          // 204,800,000 (also gh)
    size_t off_gi     = off_msgs + (size_t)R_REL * N * HID * 4;     // 153,600,000
    size_t off_tmp    = off_gi + (size_t)N * G3 * 4;                // 51,200,000 (agg / s / h1)
    size_t off_rowsum = off_tmp + (size_t)N * HID * 4;              // 200,000
    size_t off_h      = off_rowsum + (size_t)N * 4;                 // 51,200,000
    size_t off_wiht   = off_h + (size_t)N * HID * 4;                // 786,432
    size_t off_whht   = off_wiht + (size_t)HID * G3 * 4;            // 786,432
    size_t off_counts = off_whht + (size_t)HID * G3 * 4;            // 200,000 (hist, then cursor)
    size_t off_starts = off_counts + (size_t)N * 4;                 // 200,016 (N+1, padded)
    size_t off_colw   = off_starts + ((size_t)(N + 1) * 4 + 12) / 16 * 16;  // 6,400,000

    float* msgs   = (float*)(ws + off_msgs);
    float* gh     = msgs;                 // alias: msgs dead before gh written
    float* gi     = (float*)(ws + off_gi);
    float* tmp    = (float*)(ws + off_tmp);   // agg buffer; aliased as s and h1
    float* s      = tmp;
    float* h1     = tmp;
    float* rowsum = (float*)(ws + off_rowsum);
    float* h      = (float*)(ws + off_h);
    float* WihT   = (float*)(ws + off_wiht);
    float* WhhT   = (float*)(ws + off_whht);
    int*   counts = (int*)(ws + off_counts);  // reused as cursor
    int*   starts = (int*)(ws + off_starts);
    int2*  colw   = (int2*)(ws + off_colw);

    // one-time prep
    {
        int total = G3 * HID;
        transpose_w<<<(total + 255) / 256, 256, 0, stream>>>(Wih, WihT, G3, HID);
        transpose_w<<<(total + 255) / 256, 256, 0, stream>>>(Whh, WhhT, G3, HID);
    }
    hipMemsetAsync(h, 0, (size_t)N * HID * 4, stream);

    dim3 gemm_grid_h((N + 63) / 64, HID / 64);   // Nc=256
    dim3 gemm_grid_g((N + 63) / 64, G3 / 64);    // Nc=768
    int eblocks = (E_EDGES + 255) / 256;
    int agg_blocks = (N * 64 + 255) / 256;       // one wave per row

    for (int t = 0; t < T_STEPS; ++t) {
        const float* x_t = feat + (size_t)t * N * IN_DIM;
        for (int r = 0; r < R_REL; ++r) {
            size_t eoff = ((size_t)t * R_REL + r) * E_EDGES;
            const int* row_tr = erow + eoff;
            const int* col_tr = ecol + eoff;
            const float* w_tr = ew + eoff;
            // build CSR for this (t, r)
            hipMemsetAsync(counts, 0, (size_t)N * 4, stream);
            hist_rows<<<eblocks, 256, 0, stream>>>(row_tr, counts, E_EDGES);
            scan_block<<<1, 1024, 0, stream>>>(counts, starts, N);
            hipMemsetAsync(counts, 0, (size_t)N * 4, stream);   // reuse as cursor
            bin_fill<<<eblocks, 256, 0, stream>>>(row_tr, col_tr, w_tr, starts,
                                                  counts, colw, E_EDGES);
            // gather-aggregate (no atomics, no tmp memset needed)
            csr_agg<<<agg_blocks, 256, 0, stream>>>(x_t, colw, starts, tmp, rowsum, N);
            sgemm<<<gemm_grid_h, 256, 0, stream>>>(
                tmp, W_rel + (size_t)r * HID * HID, msgs + (size_t)r * N * HID,
                N, HID, b_rel + (size_t)r * HID, rowsum, 0);
        }
        attn_combine<<<N, 256, 0, stream>>>(msgs, rq, s, N);
        sgemm<<<gemm_grid_g, 256, 0, stream>>>(s, WihT, gi, N, G3, bih, nullptr, 0);
        sgemm<<<gemm_grid_g, 256, 0, stream>>>(h, WhhT, gh, N, G3, bhh, nullptr, 0);
        gru_gate<<<(N * HID + 255) / 256, 256, 0, stream>>>(gi, gh, h, N * HID);
    }

    // classifier
    sgemm<<<gemm_grid_h, 256, 0, stream>>>(h, W1, h1, N, HID, b1, nullptr, 1);
    classifier_out<<<N, 256, 0, stream>>>(h1, W2, b2, out, N);
}

// Round 3
// 10359.064 us; speedup vs baseline: 6.8819x; 1.2991x over previous
//
#include <hip/hip_runtime.h>
#include <hip/hip_bf16.h>
#include <math.h>

// Problem constants (fixed by the reference)
#define T_STEPS 6
#define N_NODES 50000
#define IN_DIM  256
#define HID     256
#define R_REL   4
#define E_EDGES 800000
#define G3      768   // 3*HID
#define MPAD    50048 // N rounded up to 128

typedef unsigned short ushort_t;
typedef __bf16 bf16x8 __attribute__((ext_vector_type(8)));
typedef float  f32x4  __attribute__((ext_vector_type(4)));

// round-to-nearest-even fp32 -> bf16 (bit-level, self-contained)
__device__ __forceinline__ ushort_t f2bf(float f) {
    unsigned u = __float_as_uint(f);
    u = (u + 0x7FFF + ((u >> 16) & 1)) >> 16;
    return (ushort_t)u;
}
__device__ __forceinline__ float bf2f(ushort_t b) {
    return __uint_as_float(((unsigned)b) << 16);
}
__device__ __forceinline__ void bsplit(float v, ushort_t& h, ushort_t& l) {
    h = f2bf(v);
    l = f2bf(v - bf2f(h));
}

// ---------------------------------------------------------------------------
// Weight prep: dst (hi/lo bf16, [Nc][K] row-major = B^T) from fp32 src.
// transposed=1: src is already [Nc][K]; else src is [K][Nc].
__global__ void prep_bt(const float* __restrict__ src, ushort_t* __restrict__ hi,
                        ushort_t* __restrict__ lo, int K, int Nc, int transposed) {
    int idx = blockIdx.x * blockDim.x + threadIdx.x;
    if (idx >= K * Nc) return;
    int n = idx / K, k = idx % K;
    float v = transposed ? src[(size_t)n * K + k] : src[(size_t)k * Nc + n];
    ushort_t h, l;
    bsplit(v, h, l);
    hi[idx] = h;
    lo[idx] = l;
}

// ---------------------------------------------------------------------------
// CSR build step 1: histogram of destination rows
__global__ void hist_rows(const int* __restrict__ row, int* __restrict__ counts, int E) {
    int e = blockIdx.x * blockDim.x + threadIdx.x;
    if (e < E) atomicAdd(&counts[row[e]], 1);
}

// CSR build step 2: exclusive prefix scan (single block, 1024 threads)
__global__ __launch_bounds__(1024)
void scan_block(const int* __restrict__ counts, int* __restrict__ starts, int n) {
    __shared__ int temp[1024];
    __shared__ int carry;
    if (threadIdx.x == 0) carry = 0;
    __syncthreads();
    for (int base = 0; base < n; base += 1024) {
        int i = base + (int)threadIdx.x;
        int v = (i < n) ? counts[i] : 0;
        temp[threadIdx.x] = v;
        __syncthreads();
#pragma unroll
        for (int off = 1; off < 1024; off <<= 1) {
            int t = (threadIdx.x >= (unsigned)off) ? temp[threadIdx.x - off] : 0;
            __syncthreads();
            temp[threadIdx.x] += t;
            __syncthreads();
        }
        int incl = temp[threadIdx.x];
        if (i < n) starts[i] = carry + incl - v;
        __syncthreads();
        if (threadIdx.x == 1023) carry += incl;
        __syncthreads();
    }
    if (threadIdx.x == 0) starts[n] = carry;
}

// CSR build step 3: scatter (col, w) into row-sorted slots
__global__ void bin_fill(const int* __restrict__ row, const int* __restrict__ col,
                         const float* __restrict__ w, const int* __restrict__ starts,
                         int* __restrict__ cursor, int2* __restrict__ colw, int E) {
    int e = blockIdx.x * blockDim.x + threadIdx.x;
    if (e >= E) return;
    int r = row[e];
    int pos = starts[r] + atomicAdd(&cursor[r], 1);
    colw[pos] = make_int2(col[e], __float_as_int(w[e]));
}

// Aggregation: one wave per destination row, gather+accumulate, write bf16 hi/lo.
__global__ void csr_agg(const float* __restrict__ x, const int2* __restrict__ colw,
                        const int* __restrict__ starts,
                        ushort_t* __restrict__ tmp_hi, ushort_t* __restrict__ tmp_lo,
                        float* __restrict__ rowsum, int N) {
    int wid  = (blockIdx.x * blockDim.x + threadIdx.x) >> 6;
    int lane = threadIdx.x & 63;
    if (wid >= N) return;
    int s0 = starts[wid], s1 = starts[wid + 1];
    float4 acc = make_float4(0.f, 0.f, 0.f, 0.f);
    float wsum = 0.f;
    for (int e = s0; e < s1; ++e) {
        int2 cw = colw[e];
        float we = __int_as_float(cw.y);
        float4 xv = ((const float4*)(x + (size_t)cw.x * 256))[lane];
        acc.x = fmaf(we, xv.x, acc.x);
        acc.y = fmaf(we, xv.y, acc.y);
        acc.z = fmaf(we, xv.z, acc.z);
        acc.w = fmaf(we, xv.w, acc.w);
        wsum += we;
    }
    ushort4 hv, lv;
    bsplit(acc.x, hv.x, lv.x);
    bsplit(acc.y, hv.y, lv.y);
    bsplit(acc.z, hv.z, lv.z);
    bsplit(acc.w, hv.w, lv.w);
    size_t o = (size_t)wid * 256 + lane * 4;
    *(ushort4*)(tmp_hi + o) = hv;
    *(ushort4*)(tmp_lo + o) = lv;
    if (lane == 0) rowsum[wid] = wsum;
}

// ---------------------------------------------------------------------------
// MFMA GEMM with hi/lo split inputs:
//   C[M,Nc] = (Ahi+Alo)[M,256] @ (Bhi+Blo)[256,Nc]  (dropping lo*lo)
// A given row-major [M][256] bf16 (hi, lo). B given TRANSPOSED: Bt [Nc][256].
// Tile 128x128, BK=64, 4 waves (2x2), each wave 64x64 = 4x4 frags of 16x16x32.
// LDS tiles XOR-swizzled (byte ^= (row&7)<<4) for conflict-free ds_read_b128.
__global__ __launch_bounds__(256, 2)
void mfma_gemm(const ushort_t* __restrict__ Ahi, const ushort_t* __restrict__ Alo,
               const ushort_t* __restrict__ Bthi, const ushort_t* __restrict__ Btlo,
               float* __restrict__ C, int M, int Nc,
               const float* __restrict__ bias, const float* __restrict__ rowscale,
               int do_relu) {
    __shared__ __align__(16) char smem[65536];
    const int AHI = 0, ALO = 16384, BHI = 32768, BLO = 49152;
    int tid = threadIdx.x;
    int m0 = blockIdx.x * 128, n0 = blockIdx.y * 128;
    int lane = tid & 63, wid = tid >> 6;
    int wr = wid >> 1, wc = wid & 1;
    int lr = lane & 15, lk = lane >> 4;
    int xorv = (lr & 7) << 4;

    f32x4 acc[4][4];
#pragma unroll
    for (int i = 0; i < 4; ++i)
#pragma unroll
        for (int j = 0; j < 4; ++j)
            acc[i][j] = (f32x4){0.f, 0.f, 0.f, 0.f};

    for (int kt = 0; kt < 4; ++kt) {
        int k0 = kt * 64;
        __syncthreads();
#pragma unroll
        for (int i = 0; i < 4; ++i) {
            int c = tid + i * 256;          // 0..1023 chunk id (16B chunks)
            int row = c >> 3, slot = c & 7; // 128 rows x 8 slots
            int ldsoff = row * 128 + ((slot * 16) ^ ((row & 7) << 4));
            size_t ga = (size_t)(m0 + row) * 256 + k0 + slot * 8;
            size_t gb = (size_t)(n0 + row) * 256 + k0 + slot * 8;
            *(int4*)(smem + AHI + ldsoff) = *(const int4*)(Ahi + ga);
            *(int4*)(smem + ALO + ldsoff) = *(const int4*)(Alo + ga);
            *(int4*)(smem + BHI + ldsoff) = *(const int4*)(Bthi + gb);
            *(int4*)(smem + BLO + ldsoff) = *(const int4*)(Btlo + gb);
        }
        __syncthreads();
#pragma unroll
        for (int kk2 = 0; kk2 < 2; ++kk2) {
            int kb = (kk2 * 64 + lk * 16) ^ xorv;
            bf16x8 ah[4], al[4], bh[4], bl[4];
#pragma unroll
            for (int f = 0; f < 4; ++f) {
                int ra = (wr * 64 + f * 16 + lr) * 128 + kb;
                int rb = (wc * 64 + f * 16 + lr) * 128 + kb;
                ah[f] = *(const bf16x8*)(smem + AHI + ra);
                al[f] = *(const bf16x8*)(smem + ALO + ra);
                bh[f] = *(const bf16x8*)(smem + BHI + rb);
                bl[f] = *(const bf16x8*)(smem + BLO + rb);
            }
#pragma unroll
            for (int fm = 0; fm < 4; ++fm)
#pragma unroll
                for (int fn = 0; fn < 4; ++fn) {
                    acc[fm][fn] = __builtin_amdgcn_mfma_f32_16x16x32_bf16(ah[fm], bh[fn], acc[fm][fn], 0, 0, 0);
                    acc[fm][fn] = __builtin_amdgcn_mfma_f32_16x16x32_bf16(ah[fm], bl[fn], acc[fm][fn], 0, 0, 0);
                    acc[fm][fn] = __builtin_amdgcn_mfma_f32_16x16x32_bf16(al[fm], bh[fn], acc[fm][fn], 0, 0, 0);
                }
        }
    }
    // epilogue: D mapping col=lane&15, row=(lane>>4)*4+reg (m89-verified)
#pragma unroll
    for (int fm = 0; fm < 4; ++fm) {
        int grb = m0 + wr * 64 + fm * 16 + lk * 4;
#pragma unroll
        for (int j = 0; j < 4; ++j) {
            int gr = grb + j;
            if (gr >= M) continue;
            float rs = rowscale ? rowscale[gr] : 1.0f;
#pragma unroll
            for (int fn = 0; fn < 4; ++fn) {
                int gc = n0 + wc * 64 + fn * 16 + lr;
                float v = acc[fm][fn][j];
                if (bias) v += rs * bias[gc];
                if (do_relu) v = fmaxf(v, 0.f);
                C[(size_t)gr * Nc + gc] = v;
            }
        }
    }
}

// ---------------------------------------------------------------------------
// Relation attention + combine: block per node, 256 threads (one per channel)
// Writes s as bf16 hi/lo (relu applied).
__global__ void attn_combine(const float* __restrict__ msgs,
                             const float* __restrict__ q,
                             ushort_t* __restrict__ s_hi, ushort_t* __restrict__ s_lo,
                             int N) {
    int n = blockIdx.x, j = threadIdx.x;
    size_t NH = (size_t)N * 256;
    size_t base = (size_t)n * 256 + j;
    float m0 = msgs[0 * NH + base];
    float m1 = msgs[1 * NH + base];
    float m2 = msgs[2 * NH + base];
    float m3 = msgs[3 * NH + base];
    float qv = q[j];
    float v0 = m0 * qv, v1 = m1 * qv, v2 = m2 * qv, v3 = m3 * qv;
#pragma unroll
    for (int off = 32; off; off >>= 1) {
        v0 += __shfl_xor(v0, off);
        v1 += __shfl_xor(v1, off);
        v2 += __shfl_xor(v2, off);
        v3 += __shfl_xor(v3, off);
    }
    __shared__ float part[4][4];
    __shared__ float alpha[4];
    int wid = j >> 6, lane = j & 63;
    if (lane == 0) {
        part[0][wid] = v0; part[1][wid] = v1; part[2][wid] = v2; part[3][wid] = v3;
    }
    __syncthreads();
    if (j == 0) {
        float d[4];
#pragma unroll
        for (int r = 0; r < 4; ++r) d[r] = part[r][0] + part[r][1] + part[r][2] + part[r][3];
        float mx = fmaxf(fmaxf(d[0], d[1]), fmaxf(d[2], d[3]));
        float e[4], sum = 0.f;
#pragma unroll
        for (int r = 0; r < 4; ++r) { e[r] = expf(d[r] - mx); sum += e[r]; }
#pragma unroll
        for (int r = 0; r < 4; ++r) alpha[r] = e[r] / sum;
    }
    __syncthreads();
    float sv = alpha[0] * m0 + alpha[1] * m1 + alpha[2] * m2 + alpha[3] * m3;
    sv = fmaxf(sv, 0.f);
    ushort_t h, l;
    bsplit(sv, h, l);
    s_hi[base] = h;
    s_lo[base] = l;
}

// ---------------------------------------------------------------------------
// GRU gate fuse: h = (1-z)*n + z*h; also emit bf16 hi/lo of new h
__global__ void gru_gate(const float* __restrict__ gi, const float* __restrict__ gh,
                         float* __restrict__ h,
                         ushort_t* __restrict__ h_hi, ushort_t* __restrict__ h_lo,
                         int total) {
    int idx = blockIdx.x * blockDim.x + threadIdx.x;
    if (idx >= total) return;
    int i = idx >> 8, j = idx & 255;
    size_t b = (size_t)i * 768;
    float ir = gi[b + j],       hr = gh[b + j];
    float iz = gi[b + 256 + j], hz = gh[b + 256 + j];
    float in_ = gi[b + 512 + j], hn = gh[b + 512 + j];
    float r = 1.f / (1.f + expf(-(ir + hr)));
    float z = 1.f / (1.f + expf(-(iz + hz)));
    float ng = tanhf(in_ + r * hn);
    float hv = h[idx];
    float hnew = (1.f - z) * ng + z * hv;
    h[idx] = hnew;
    ushort_t hh, hl;
    bsplit(hnew, hh, hl);
    h_hi[idx] = hh;
    h_lo[idx] = hl;
}

// ---------------------------------------------------------------------------
// out[n] = dot(h1[n,:], W2[:,0]) + b2[0]
__global__ void classifier_out(const float* __restrict__ h1, const float* __restrict__ W2,
                               const float* __restrict__ b2, float* __restrict__ out, int N) {
    int n = blockIdx.x, j = threadIdx.x;
    float v = h1[(size_t)n * 256 + j] * W2[j];
#pragma unroll
    for (int off = 32; off; off >>= 1) v += __shfl_xor(v, off);
    __shared__ float part[4];
    if ((j & 63) == 0) part[j >> 6] = v;
    __syncthreads();
    if (j == 0) out[n] = part[0] + part[1] + part[2] + part[3] + b2[0];
}

// ---------------------------------------------------------------------------
extern "C" void kernel_launch(void* const* d_in, const int* in_sizes, int n_in,
                              void* d_out, int out_size, void* d_ws, size_t ws_size,
                              hipStream_t stream) {
    const float* feat  = (const float*)d_in[0];
    const int*   erow  = (const int*)d_in[1];
    const int*   ecol  = (const int*)d_in[2];
    const float* ew    = (const float*)d_in[3];
    const float* W_rel = (const float*)d_in[4];
    const float* b_rel = (const float*)d_in[5];
    const float* rq    = (const float*)d_in[6];
    const float* Wih   = (const float*)d_in[7];
    const float* Whh   = (const float*)d_in[8];
    const float* bih   = (const float*)d_in[9];
    const float* bhh   = (const float*)d_in[10];
    const float* W1    = (const float*)d_in[11];
    const float* b1    = (const float*)d_in[12];
    const float* W2    = (const float*)d_in[13];
    const float* b2    = (const float*)d_in[14];
    float* out = (float*)d_out;

    const int N = N_NODES;
    char* ws = (char*)d_ws;

    // --- workspace layout (bytes, all 16B aligned) ---
    // P region: msgs [4][N][256] f32 (204.8MB); gi [N][768] f32 and h1 [N][256] f32 alias it
    // Q region: tmp_hi/lo + s_hi/lo (bf16, MPAD rows); gh [N][768] f32 aliases it
    size_t off_P      = 0;                               // 204,800,000
    size_t off_Q      = 204800000;                       // 153,600,000
    size_t off_h      = 358400000;                       // 51,200,000
    size_t off_h_hi   = 409600000;                       // 25,624,576 (MPAD*512)
    size_t off_h_lo   = 435224576;                       // 25,624,576
    size_t off_rowsum = 460849152;                       // 200,192 (MPAD*4)
    size_t off_wrelh  = 461049344;                       // 524,288
    size_t off_wrell  = 461573632;                       // 524,288
    size_t off_wihh   = 462097920;                       // 393,216
    size_t off_wihl   = 462491136;                       // 393,216
    size_t off_whhh   = 462884352;                       // 393,216
    size_t off_whhl   = 463277568;                       // 393,216
    size_t off_w1h    = 463670784;                       // 131,072
    size_t off_w1l    = 463801856;                       // 131,072
    size_t off_counts = 463932928;                       // 200,000
    size_t off_starts = 464132928;                       // 200,032
    size_t off_colw   = 464332960;                       // 6,400,000  (end ~470.7MB)

    float*    msgs   = (float*)(ws + off_P);
    float*    gi     = (float*)(ws + off_P);                      // alias (msgs dead)
    float*    h1     = (float*)(ws + off_P);                      // alias (gi dead)
    ushort_t* tmp_hi = (ushort_t*)(ws + off_Q);
    ushort_t* tmp_lo = (ushort_t*)(ws + off_Q + 25624576);
    ushort_t* s_hi   = (ushort_t*)(ws + off_Q + 51249152);
    ushort_t* s_lo   = (ushort_t*)(ws + off_Q + 76873728);
    float*    gh     = (float*)(ws + off_Q);                      // alias (tmp/s dead)
    float*    h      = (float*)(ws + off_h);
    ushort_t* h_hi   = (ushort_t*)(ws + off_h_hi);
    ushort_t* h_lo   = (ushort_t*)(ws + off_h_lo);
    float*    rowsum = (float*)(ws + off_rowsum);
    ushort_t* wrel_h = (ushort_t*)(ws + off_wrelh);
    ushort_t* wrel_l = (ushort_t*)(ws + off_wrell);
    ushort_t* wih_h  = (ushort_t*)(ws + off_wihh);
    ushort_t* wih_l  = (ushort_t*)(ws + off_wihl);
    ushort_t* whh_h  = (ushort_t*)(ws + off_whhh);
    ushort_t* whh_l  = (ushort_t*)(ws + off_whhl);
    ushort_t* w1_h   = (ushort_t*)(ws + off_w1h);
    ushort_t* w1_l   = (ushort_t*)(ws + off_w1l);
    int*      counts = (int*)(ws + off_counts);
    int*      starts = (int*)(ws + off_starts);
    int2*     colw   = (int2*)(ws + off_colw);

    // one-time prep: split weights to bf16 hi/lo, B^T layout [Nc][K]
    for (int r = 0; r < R_REL; ++r)
        prep_bt<<<(65536 + 255) / 256, 256, 0, stream>>>(
            W_rel + (size_t)r * 65536, wrel_h + (size_t)r * 65536,
            wrel_l + (size_t)r * 65536, 256, 256, 0);
    prep_bt<<<(G3 * 256 + 255) / 256, 256, 0, stream>>>(Wih, wih_h, wih_l, 256, G3, 1);
    prep_bt<<<(G3 * 256 + 255) / 256, 256, 0, stream>>>(Whh, whh_h, whh_l, 256, G3, 1);
    prep_bt<<<(65536 + 255) / 256, 256, 0, stream>>>(W1, w1_h, w1_l, 256, 256, 0);

    hipMemsetAsync(h, 0, (size_t)N * HID * 4, stream);
    hipMemsetAsync(ws + off_h_hi, 0, 2 * 25624576, stream);  // h_hi + h_lo (incl. pad rows)

    dim3 g_rel((MPAD / 128), 2);   // Nc=256
    dim3 g_g3((MPAD / 128), 6);    // Nc=768
    int eblocks = (E_EDGES + 255) / 256;
    int agg_blocks = (N * 64 + 255) / 256;

    for (int t = 0; t < T_STEPS; ++t) {
        const float* x_t = feat + (size_t)t * N * IN_DIM;
        for (int r = 0; r < R_REL; ++r) {
            size_t eoff = ((size_t)t * R_REL + r) * E_EDGES;
            hipMemsetAsync(counts, 0, (size_t)N * 4, stream);
            hist_rows<<<eblocks, 256, 0, stream>>>(erow + eoff, counts, E_EDGES);
            scan_block<<<1, 1024, 0, stream>>>(counts, starts, N);
            hipMemsetAsync(counts, 0, (size_t)N * 4, stream);
            bin_fill<<<eblocks, 256, 0, stream>>>(erow + eoff, ecol + eoff, ew + eoff,
                                                  starts, counts, colw, E_EDGES);
            csr_agg<<<agg_blocks, 256, 0, stream>>>(x_t, colw, starts, tmp_hi, tmp_lo,
                                                    rowsum, N);
            mfma_gemm<<<g_rel, 256, 0, stream>>>(
                tmp_hi, tmp_lo, wrel_h + (size_t)r * 65536, wrel_l + (size_t)r * 65536,
                msgs + (size_t)r * N * HID, N, 256, b_rel + (size_t)r * HID, rowsum, 0);
        }
        attn_combine<<<N, 256, 0, stream>>>(msgs, rq, s_hi, s_lo, N);
        mfma_gemm<<<g_g3, 256, 0, stream>>>(s_hi, s_lo, wih_h, wih_l, gi, N, G3,
                                            bih, nullptr, 0);
        mfma_gemm<<<g_g3, 256, 0, stream>>>(h_hi, h_lo, whh_h, whh_l, gh, N, G3,
                                            bhh, nullptr, 0);
        gru_gate<<<(N * HID + 255) / 256, 256, 0, stream>>>(gi, gh, h, h_hi, h_lo,
                                                            N * HID);
    }

    // classifier
    mfma_gemm<<<g_rel, 256, 0, stream>>>(h_hi, h_lo, w1_h, w1_l, h1, N, 256,
                                         b1, nullptr, 1);
    classifier_out<<<N, 256, 0, stream>>>(h1, W2, b2, out, N);
}

// Round 4
// 7611.031 us; speedup vs baseline: 9.3666x; 1.3611x over previous
//
#include <hip/hip_runtime.h>
#include <hip/hip_bf16.h>
#include <math.h>

// Problem constants (fixed by the reference)
#define T_STEPS 6
#define N_NODES 50000
#define IN_DIM  256
#define HID     256
#define R_REL   4
#define E_EDGES 800000
#define G3      768    // 3*HID
#define MPAD    50048  // N rounded up to 128
#define NTR     24     // T*R
#define ETOT    19200000
#define NTOT    1200000  // NTR*N

typedef unsigned short ushort_t;
typedef __bf16 bf16x8 __attribute__((ext_vector_type(8)));
typedef float  f32x4  __attribute__((ext_vector_type(4)));

// round-to-nearest-even fp32 -> bf16 (bit-level, self-contained)
__device__ __forceinline__ ushort_t f2bf(float f) {
    unsigned u = __float_as_uint(f);
    u = (u + 0x7FFF + ((u >> 16) & 1)) >> 16;
    return (ushort_t)u;
}
__device__ __forceinline__ float bf2f(ushort_t b) {
    return __uint_as_float(((unsigned)b) << 16);
}
__device__ __forceinline__ void bsplit(float v, ushort_t& h, ushort_t& l) {
    h = f2bf(v);
    l = f2bf(v - bf2f(h));
}

// ---------------------------------------------------------------------------
// Weight prep: dst (hi/lo bf16, [Nc][K] row-major = B^T) from fp32 src.
__global__ void prep_bt(const float* __restrict__ src, ushort_t* __restrict__ hi,
                        ushort_t* __restrict__ lo, int K, int Nc, int transposed) {
    int idx = blockIdx.x * blockDim.x + threadIdx.x;
    if (idx >= K * Nc) return;
    int n = idx / K, k = idx % K;
    float v = transposed ? src[(size_t)n * K + k] : src[(size_t)k * Nc + n];
    ushort_t h, l;
    bsplit(v, h, l);
    hi[idx] = h;
    lo[idx] = l;
}

// ---------------------------------------------------------------------------
// Batched CSR build over all 24 (t,r) graphs at once.
// counts[tr*N + row] histogram:
__global__ void hist_all(const int* __restrict__ row, int* __restrict__ counts) {
    int ge = blockIdx.x * blockDim.x + threadIdx.x;
    if (ge >= ETOT) return;
    int tr = ge / E_EDGES;
    atomicAdd(&counts[tr * N_NODES + row[ge]], 1);
}

// scan step 1: per-block (1024) exclusive scan; emit block sums
__global__ __launch_bounds__(1024)
void scan1(const int* __restrict__ counts, int* __restrict__ starts,
           int* __restrict__ bsums, int n) {
    __shared__ int temp[1024];
    int i = blockIdx.x * 1024 + threadIdx.x;
    int v = (i < n) ? counts[i] : 0;
    temp[threadIdx.x] = v;
    __syncthreads();
#pragma unroll
    for (int off = 1; off < 1024; off <<= 1) {
        int t = (threadIdx.x >= (unsigned)off) ? temp[threadIdx.x - off] : 0;
        __syncthreads();
        temp[threadIdx.x] += t;
        __syncthreads();
    }
    int incl = temp[threadIdx.x];
    if (i < n) starts[i] = incl - v;
    if (threadIdx.x == 1023) bsums[blockIdx.x] = incl;
}

// scan step 2: single-block exclusive scan of block sums (n up to ~2k)
__global__ __launch_bounds__(1024)
void scan_block(const int* __restrict__ counts, int* __restrict__ starts, int n) {
    __shared__ int temp[1024];
    __shared__ int carry;
    if (threadIdx.x == 0) carry = 0;
    __syncthreads();
    for (int base = 0; base < n; base += 1024) {
        int i = base + (int)threadIdx.x;
        int v = (i < n) ? counts[i] : 0;
        temp[threadIdx.x] = v;
        __syncthreads();
#pragma unroll
        for (int off = 1; off < 1024; off <<= 1) {
            int t = (threadIdx.x >= (unsigned)off) ? temp[threadIdx.x - off] : 0;
            __syncthreads();
            temp[threadIdx.x] += t;
            __syncthreads();
        }
        int incl = temp[threadIdx.x];
        if (i < n) starts[i] = carry + incl - v;
        __syncthreads();
        if (threadIdx.x == 1023) carry += incl;
        __syncthreads();
    }
    if (threadIdx.x == 0) starts[n] = carry;
}

// scan step 3: add block offsets; write sentinel
__global__ __launch_bounds__(1024)
void scan3(int* __restrict__ starts, const int* __restrict__ bsumsX, int n) {
    int i = blockIdx.x * 1024 + threadIdx.x;
    if (i < n) starts[i] += bsumsX[blockIdx.x];
    if (i == 0) starts[n] = ETOT;
}

// bin-fill: scatter (col, w) into globally row-sorted slots
__global__ void bin_fill_all(const int* __restrict__ row, const int* __restrict__ col,
                             const float* __restrict__ w, const int* __restrict__ starts,
                             int* __restrict__ cursor, int2* __restrict__ colw) {
    int ge = blockIdx.x * blockDim.x + threadIdx.x;
    if (ge >= ETOT) return;
    int c = (ge / E_EDGES) * N_NODES + row[ge];
    int pos = starts[c] + atomicAdd(&cursor[c], 1);
    colw[pos] = make_int2(col[ge], __float_as_int(w[ge]));
}

// ---------------------------------------------------------------------------
// Aggregation, batched over the 4 relations of one t (blockIdx.y = r).
// One wave per destination row; gather x rows, accumulate, write bf16 hi/lo.
__global__ void csr_agg_t(const float* __restrict__ x, const int2* __restrict__ colw,
                          const int* __restrict__ startsT,
                          ushort_t* __restrict__ tmp_hi, ushort_t* __restrict__ tmp_lo,
                          float* __restrict__ rowsum) {
    int wid  = (blockIdx.x * blockDim.x + threadIdx.x) >> 6;
    int lane = threadIdx.x & 63;
    int r    = blockIdx.y;
    if (wid >= N_NODES) return;
    int s0 = startsT[r * N_NODES + wid], s1 = startsT[r * N_NODES + wid + 1];
    float4 acc = make_float4(0.f, 0.f, 0.f, 0.f);
    float wsum = 0.f;
    for (int e = s0; e < s1; ++e) {
        int2 cw = colw[e];
        float we = __int_as_float(cw.y);
        float4 xv = ((const float4*)(x + (size_t)cw.x * 256))[lane];
        acc.x = fmaf(we, xv.x, acc.x);
        acc.y = fmaf(we, xv.y, acc.y);
        acc.z = fmaf(we, xv.z, acc.z);
        acc.w = fmaf(we, xv.w, acc.w);
        wsum += we;
    }
    ushort4 hv, lv;
    bsplit(acc.x, hv.x, lv.x);
    bsplit(acc.y, hv.y, lv.y);
    bsplit(acc.z, hv.z, lv.z);
    bsplit(acc.w, hv.w, lv.w);
    size_t o = ((size_t)r * MPAD + wid) * 256 + lane * 4;
    *(ushort4*)(tmp_hi + o) = hv;
    *(ushort4*)(tmp_lo + o) = lv;
    if (lane == 0) rowsum[r * MPAD + wid] = wsum;
}

// ---------------------------------------------------------------------------
// MFMA GEMM, hi/lo split: C = (Ahi+Alo) @ (Bhi+Blo), dropping lo*lo.
// A row-major [M][256] bf16; B transposed [Nc][256] bf16.
// Tile 128x128, BK=64, 4 waves (2x2). blockIdx.z selects batched operand set.
__global__ __launch_bounds__(256, 2)
void mfma_gemm(const ushort_t* __restrict__ Ahi, const ushort_t* __restrict__ Alo,
               const ushort_t* __restrict__ Bthi, const ushort_t* __restrict__ Btlo,
               float* __restrict__ C, int M, int Nc,
               const float* __restrict__ bias, const float* __restrict__ rowscale,
               int do_relu, size_t aZ, size_t bZ, size_t cZ, int biasZ, int rsZ) {
    int z = blockIdx.z;
    Ahi  += (size_t)z * aZ;  Alo  += (size_t)z * aZ;
    Bthi += (size_t)z * bZ;  Btlo += (size_t)z * bZ;
    C    += (size_t)z * cZ;
    if (bias)     bias     += (size_t)z * biasZ;
    if (rowscale) rowscale += (size_t)z * rsZ;

    __shared__ __align__(16) char smem[65536];
    const int AHI = 0, ALO = 16384, BHI = 32768, BLO = 49152;
    int tid = threadIdx.x;
    int m0 = blockIdx.x * 128, n0 = blockIdx.y * 128;
    int lane = tid & 63, wid = tid >> 6;
    int wr = wid >> 1, wc = wid & 1;
    int lr = lane & 15, lk = lane >> 4;
    int xorv = (lr & 7) << 4;

    f32x4 acc[4][4];
#pragma unroll
    for (int i = 0; i < 4; ++i)
#pragma unroll
        for (int j = 0; j < 4; ++j)
            acc[i][j] = (f32x4){0.f, 0.f, 0.f, 0.f};

    for (int kt = 0; kt < 4; ++kt) {
        int k0 = kt * 64;
        __syncthreads();
#pragma unroll
        for (int i = 0; i < 4; ++i) {
            int c = tid + i * 256;          // 0..1023 chunk id (16B chunks)
            int row = c >> 3, slot = c & 7; // 128 rows x 8 slots
            int ldsoff = row * 128 + ((slot * 16) ^ ((row & 7) << 4));
            size_t ga = (size_t)(m0 + row) * 256 + k0 + slot * 8;
            size_t gb = (size_t)(n0 + row) * 256 + k0 + slot * 8;
            *(int4*)(smem + AHI + ldsoff) = *(const int4*)(Ahi + ga);
            *(int4*)(smem + ALO + ldsoff) = *(const int4*)(Alo + ga);
            *(int4*)(smem + BHI + ldsoff) = *(const int4*)(Bthi + gb);
            *(int4*)(smem + BLO + ldsoff) = *(const int4*)(Btlo + gb);
        }
        __syncthreads();
#pragma unroll
        for (int kk2 = 0; kk2 < 2; ++kk2) {
            int kb = (kk2 * 64 + lk * 16) ^ xorv;
            bf16x8 ah[4], al[4], bh[4], bl[4];
#pragma unroll
            for (int f = 0; f < 4; ++f) {
                int ra = (wr * 64 + f * 16 + lr) * 128 + kb;
                int rb = (wc * 64 + f * 16 + lr) * 128 + kb;
                ah[f] = *(const bf16x8*)(smem + AHI + ra);
                al[f] = *(const bf16x8*)(smem + ALO + ra);
                bh[f] = *(const bf16x8*)(smem + BHI + rb);
                bl[f] = *(const bf16x8*)(smem + BLO + rb);
            }
#pragma unroll
            for (int fm = 0; fm < 4; ++fm)
#pragma unroll
                for (int fn = 0; fn < 4; ++fn) {
                    acc[fm][fn] = __builtin_amdgcn_mfma_f32_16x16x32_bf16(ah[fm], bh[fn], acc[fm][fn], 0, 0, 0);
                    acc[fm][fn] = __builtin_amdgcn_mfma_f32_16x16x32_bf16(ah[fm], bl[fn], acc[fm][fn], 0, 0, 0);
                    acc[fm][fn] = __builtin_amdgcn_mfma_f32_16x16x32_bf16(al[fm], bh[fn], acc[fm][fn], 0, 0, 0);
                }
        }
    }
    // epilogue: D mapping col=lane&15, row=(lane>>4)*4+reg (m89-verified)
#pragma unroll
    for (int fm = 0; fm < 4; ++fm) {
        int grb = m0 + wr * 64 + fm * 16 + lk * 4;
#pragma unroll
        for (int j = 0; j < 4; ++j) {
            int gr = grb + j;
            if (gr >= M) continue;
            float rs = rowscale ? rowscale[gr] : 1.0f;
#pragma unroll
            for (int fn = 0; fn < 4; ++fn) {
                int gc = n0 + wc * 64 + fn * 16 + lr;
                float v = acc[fm][fn][j];
                if (bias) v += rs * bias[gc];
                if (do_relu) v = fmaxf(v, 0.f);
                C[(size_t)gr * Nc + gc] = v;
            }
        }
    }
}

// ---------------------------------------------------------------------------
// Relation attention + combine: block per node, 256 threads (one per channel)
__global__ void attn_combine(const float* __restrict__ msgs,
                             const float* __restrict__ q,
                             ushort_t* __restrict__ s_hi, ushort_t* __restrict__ s_lo,
                             int N) {
    int n = blockIdx.x, j = threadIdx.x;
    size_t NH = (size_t)N * 256;
    size_t base = (size_t)n * 256 + j;
    float m0 = msgs[0 * NH + base];
    float m1 = msgs[1 * NH + base];
    float m2 = msgs[2 * NH + base];
    float m3 = msgs[3 * NH + base];
    float qv = q[j];
    float v0 = m0 * qv, v1 = m1 * qv, v2 = m2 * qv, v3 = m3 * qv;
#pragma unroll
    for (int off = 32; off; off >>= 1) {
        v0 += __shfl_xor(v0, off);
        v1 += __shfl_xor(v1, off);
        v2 += __shfl_xor(v2, off);
        v3 += __shfl_xor(v3, off);
    }
    __shared__ float part[4][4];
    __shared__ float alpha[4];
    int wid = j >> 6, lane = j & 63;
    if (lane == 0) {
        part[0][wid] = v0; part[1][wid] = v1; part[2][wid] = v2; part[3][wid] = v3;
    }
    __syncthreads();
    if (j == 0) {
        float d[4];
#pragma unroll
        for (int r = 0; r < 4; ++r) d[r] = part[r][0] + part[r][1] + part[r][2] + part[r][3];
        float mx = fmaxf(fmaxf(d[0], d[1]), fmaxf(d[2], d[3]));
        float e[4], sum = 0.f;
#pragma unroll
        for (int r = 0; r < 4; ++r) { e[r] = expf(d[r] - mx); sum += e[r]; }
#pragma unroll
        for (int r = 0; r < 4; ++r) alpha[r] = e[r] / sum;
    }
    __syncthreads();
    float sv = alpha[0] * m0 + alpha[1] * m1 + alpha[2] * m2 + alpha[3] * m3;
    sv = fmaxf(sv, 0.f);
    ushort_t h, l;
    bsplit(sv, h, l);
    s_hi[base] = h;
    s_lo[base] = l;
}

// ---------------------------------------------------------------------------
// GRU gate fuse (float4-vectorized): h = (1-z)*n + z*h; emit bf16 hi/lo of h
__global__ void gru_gate(const float* __restrict__ gi, const float* __restrict__ gh,
                         float* __restrict__ h,
                         ushort_t* __restrict__ h_hi, ushort_t* __restrict__ h_lo,
                         int total4) {
    int idx = blockIdx.x * blockDim.x + threadIdx.x;
    if (idx >= total4) return;
    int i = idx >> 6, j = (idx & 63) * 4;
    size_t b = (size_t)i * 768 + j;
    float4 ir = *(const float4*)(gi + b);
    float4 iz = *(const float4*)(gi + b + 256);
    float4 in_ = *(const float4*)(gi + b + 512);
    float4 hr = *(const float4*)(gh + b);
    float4 hz = *(const float4*)(gh + b + 256);
    float4 hn = *(const float4*)(gh + b + 512);
    size_t o = (size_t)i * 256 + j;
    float4 hv = *(const float4*)(h + o);
    float4 hnew;
    const float* irp = &ir.x; const float* izp = &iz.x; const float* inp = &in_.x;
    const float* hrp = &hr.x; const float* hzp = &hz.x; const float* hnp = &hn.x;
    const float* hvp = &hv.x; float* hop = &hnew.x;
    ushort4 hh4, hl4;
    ushort_t* hhp = &hh4.x; ushort_t* hlp = &hl4.x;
#pragma unroll
    for (int k = 0; k < 4; ++k) {
        float r = 1.f / (1.f + expf(-(irp[k] + hrp[k])));
        float z = 1.f / (1.f + expf(-(izp[k] + hzp[k])));
        float ng = tanhf(inp[k] + r * hnp[k]);
        float v = (1.f - z) * ng + z * hvp[k];
        hop[k] = v;
        bsplit(v, hhp[k], hlp[k]);
    }
    *(float4*)(h + o) = hnew;
    *(ushort4*)(h_hi + o) = hh4;
    *(ushort4*)(h_lo + o) = hl4;
}

// ---------------------------------------------------------------------------
// out[n] = dot(h1[n,:], W2[:,0]) + b2[0]
__global__ void classifier_out(const float* __restrict__ h1, const float* __restrict__ W2,
                               const float* __restrict__ b2, float* __restrict__ out, int N) {
    int n = blockIdx.x, j = threadIdx.x;
    float v = h1[(size_t)n * 256 + j] * W2[j];
#pragma unroll
    for (int off = 32; off; off >>= 1) v += __shfl_xor(v, off);
    __shared__ float part[4];
    if ((j & 63) == 0) part[j >> 6] = v;
    __syncthreads();
    if (j == 0) out[n] = part[0] + part[1] + part[2] + part[3] + b2[0];
}

// ---------------------------------------------------------------------------
extern "C" void kernel_launch(void* const* d_in, const int* in_sizes, int n_in,
                              void* d_out, int out_size, void* d_ws, size_t ws_size,
                              hipStream_t stream) {
    const float* feat  = (const float*)d_in[0];
    const int*   erow  = (const int*)d_in[1];
    const int*   ecol  = (const int*)d_in[2];
    const float* ew    = (const float*)d_in[3];
    const float* W_rel = (const float*)d_in[4];
    const float* b_rel = (const float*)d_in[5];
    const float* rq    = (const float*)d_in[6];
    const float* Wih   = (const float*)d_in[7];
    const float* Whh   = (const float*)d_in[8];
    const float* bih   = (const float*)d_in[9];
    const float* bhh   = (const float*)d_in[10];
    const float* W1    = (const float*)d_in[11];
    const float* b1    = (const float*)d_in[12];
    const float* W2    = (const float*)d_in[13];
    const float* b2    = (const float*)d_in[14];
    float* out = (float*)d_out;

    const int N = N_NODES;
    char* ws = (char*)d_ws;

    // --- workspace layout (bytes, 16B aligned; total ~735 MB) ---
    size_t off_msgs   = 0;            // [4][N][256] f32 = 204,800,000 ; aliases gi [N][768], h1
    size_t off_tmp    = 204800000;    // tmp_hi [4][MPAD][256] bf16 = 102,498,304
    size_t off_tmplo  = 307298304;    // tmp_lo 102,498,304 ; gh [N][768] f32 aliases off_tmp
    size_t off_colw   = 409796608;    // [24E] int2 = 153,600,000
    size_t off_h      = 563396608;    // [N][256] f32 = 51,200,000
    size_t off_hhi    = 614596608;    // MPAD*256*2 = 25,624,576
    size_t off_hlo    = 640221184;    // 25,624,576
    size_t off_shi    = 665845760;    // 25,624,576
    size_t off_slo    = 691470336;    // 25,624,576
    size_t off_rowsum = 717094912;    // [4][MPAD] f32 = 800,768
    size_t off_wrelh  = 717895680;    // 524,288
    size_t off_wrell  = 718419968;    // 524,288
    size_t off_wihh   = 718944256;    // 393,216
    size_t off_wihl   = 719337472;    // 393,216
    size_t off_whhh   = 719730688;    // 393,216
    size_t off_whhl   = 720123904;    // 393,216
    size_t off_w1h    = 720517120;    // 131,072
    size_t off_w1l    = 720648192;    // 131,072
    size_t off_counts = 720779264;    // 4,800,000
    size_t off_cursor = 725579264;    // 4,800,000
    size_t off_starts = 730379264;    // (NTOT+1)*4 -> 4,800,016
    size_t off_bsums  = 735179280;    // 8,192
    size_t off_bsumsX = 735187472;    // 8,192   (end ~735.2 MB)

    float*    msgs   = (float*)(ws + off_msgs);
    float*    gi     = (float*)(ws + off_msgs);     // alias (msgs dead)
    float*    h1     = (float*)(ws + off_msgs);     // alias (gi dead)
    ushort_t* tmp_hi = (ushort_t*)(ws + off_tmp);
    ushort_t* tmp_lo = (ushort_t*)(ws + off_tmplo);
    float*    gh     = (float*)(ws + off_tmp);      // alias (tmp dead when gh written)
    int2*     colw   = (int2*)(ws + off_colw);
    float*    h      = (float*)(ws + off_h);
    ushort_t* h_hi   = (ushort_t*)(ws + off_hhi);
    ushort_t* h_lo   = (ushort_t*)(ws + off_hlo);
    ushort_t* s_hi   = (ushort_t*)(ws + off_shi);
    ushort_t* s_lo   = (ushort_t*)(ws + off_slo);
    float*    rowsum = (float*)(ws + off_rowsum);
    ushort_t* wrel_h = (ushort_t*)(ws + off_wrelh);
    ushort_t* wrel_l = (ushort_t*)(ws + off_wrell);
    ushort_t* wih_h  = (ushort_t*)(ws + off_wihh);
    ushort_t* wih_l  = (ushort_t*)(ws + off_wihl);
    ushort_t* whh_h  = (ushort_t*)(ws + off_whhh);
    ushort_t* whh_l  = (ushort_t*)(ws + off_whhl);
    ushort_t* w1_h   = (ushort_t*)(ws + off_w1h);
    ushort_t* w1_l   = (ushort_t*)(ws + off_w1l);
    int*      counts = (int*)(ws + off_counts);
    int*      cursor = (int*)(ws + off_cursor);
    int*      starts = (int*)(ws + off_starts);
    int*      bsums  = (int*)(ws + off_bsums);
    int*      bsumsX = (int*)(ws + off_bsumsX);

    const int NB_SCAN = (NTOT + 1023) / 1024;   // 1172

    // one-time prep: weights -> bf16 hi/lo B^T
    for (int r = 0; r < R_REL; ++r)
        prep_bt<<<(65536 + 255) / 256, 256, 0, stream>>>(
            W_rel + (size_t)r * 65536, wrel_h + (size_t)r * 65536,
            wrel_l + (size_t)r * 65536, 256, 256, 0);
    prep_bt<<<(G3 * 256 + 255) / 256, 256, 0, stream>>>(Wih, wih_h, wih_l, 256, G3, 1);
    prep_bt<<<(G3 * 256 + 255) / 256, 256, 0, stream>>>(Whh, whh_h, whh_l, 256, G3, 1);
    prep_bt<<<(65536 + 255) / 256, 256, 0, stream>>>(W1, w1_h, w1_l, 256, 256, 0);

    hipMemsetAsync(h, 0, (size_t)N * HID * 4, stream);
    hipMemsetAsync(ws + off_hhi, 0, 2 * 25624576, stream);       // h_hi + h_lo
    hipMemsetAsync(counts, 0, 2 * 4800000, stream);              // counts + cursor

    // batched CSR build for all 24 (t,r) graphs
    int eblocks = (ETOT + 255) / 256;
    hist_all<<<eblocks, 256, 0, stream>>>(erow, counts);
    scan1<<<NB_SCAN, 1024, 0, stream>>>(counts, starts, bsums, NTOT);
    scan_block<<<1, 1024, 0, stream>>>(bsums, bsumsX, NB_SCAN);
    scan3<<<NB_SCAN, 1024, 0, stream>>>(starts, bsumsX, NTOT);
    bin_fill_all<<<eblocks, 256, 0, stream>>>(erow, ecol, ew, starts, cursor, colw);

    dim3 g_rel(MPAD / 128, 2, 4);   // 4 relations, Nc=256
    dim3 g_g3(MPAD / 128, 6, 1);    // Nc=768
    dim3 g_cls(MPAD / 128, 2, 1);
    dim3 agg_grid((N + 3) / 4, 4);  // 4 waves/block, one wave per row; y = relation

    for (int t = 0; t < T_STEPS; ++t) {
        const float* x_t = feat + (size_t)t * N * IN_DIM;
        csr_agg_t<<<agg_grid, 256, 0, stream>>>(
            x_t, colw, starts + (size_t)t * R_REL * N, tmp_hi, tmp_lo, rowsum);
        mfma_gemm<<<g_rel, 256, 0, stream>>>(
            tmp_hi, tmp_lo, wrel_h, wrel_l, msgs, N, 256, b_rel, rowsum, 0,
            (size_t)MPAD * 256, 65536, (size_t)N * 256, 256, MPAD);
        attn_combine<<<N, 256, 0, stream>>>(msgs, rq, s_hi, s_lo, N);
        mfma_gemm<<<g_g3, 256, 0, stream>>>(s_hi, s_lo, wih_h, wih_l, gi, N, G3,
                                            bih, nullptr, 0, 0, 0, 0, 0, 0);
        mfma_gemm<<<g_g3, 256, 0, stream>>>(h_hi, h_lo, whh_h, whh_l, gh, N, G3,
                                            bhh, nullptr, 0, 0, 0, 0, 0, 0);
        gru_gate<<<(N * 64 + 255) / 256, 256, 0, stream>>>(gi, gh, h, h_hi, h_lo, N * 64);
    }

    // classifier
    mfma_gemm<<<g_cls, 256, 0, stream>>>(h_hi, h_lo, w1_h, w1_l, h1, N, 256,
                                         b1, nullptr, 1, 0, 0, 0, 0, 0);
    classifier_out<<<N, 256, 0, stream>>>(h1, W2, b2, out, N);
}